// Round 1
// baseline (78.633 us; speedup 1.0000x reference)
//
#include <hip/hip_runtime.h>

#define HID 128
#define FEAT 16
#define N_PER 100000
#define NUM_ACTIONS 75000

// ws float layout:
// [0..143]   wg   = glob_W @ p            (144)
// [144..287] wn   = node_W @ p            (144)
// [288..415] qe   = (e2_W @ p)[0:128]     (128)
// [416..687] w1   = e1_W @ (e2_W@p)[128:] (272)
// [688] cg = glob_b.p   [689] cn = node_b.p
// [690] ce = e1_b.qEE + e2_b.p            [691] pb = pol_b

__global__ __launch_bounds__(1024) void fold_weights_kernel(
    const float* __restrict__ glob_W, const float* __restrict__ glob_b,
    const float* __restrict__ node_W, const float* __restrict__ node_b,
    const float* __restrict__ e1_W,  const float* __restrict__ e1_b,
    const float* __restrict__ e2_W,  const float* __restrict__ e2_b,
    const float* __restrict__ pol_W, const float* __restrict__ pol_b,
    float* __restrict__ ws)
{
    __shared__ float qEE[HID];
    __shared__ float s_ce2;
    const int t = threadIdx.x;

    if (t < 144) {                       // wg
        float acc = 0.f;
        for (int j = 0; j < HID; ++j) acc += glob_W[t * HID + j] * pol_W[j];
        ws[t] = acc;
    } else if (t < 288) {                // wn
        const int k = t - 144;
        float acc = 0.f;
        for (int j = 0; j < HID; ++j) acc += node_W[k * HID + j] * pol_W[j];
        ws[144 + k] = acc;
    } else if (t < 544) {                // q = e2_W @ p
        const int k = t - 288;           // 0..255
        float acc = 0.f;
        for (int j = 0; j < HID; ++j) acc += e2_W[k * HID + j] * pol_W[j];
        if (k < HID) ws[288 + k] = acc;  // qe
        else         qEE[k - HID] = acc;
    } else if (t == 544) {               // cg
        float acc = 0.f;
        for (int j = 0; j < HID; ++j) acc += glob_b[j] * pol_W[j];
        ws[688] = acc;
    } else if (t == 545) {               // cn
        float acc = 0.f;
        for (int j = 0; j < HID; ++j) acc += node_b[j] * pol_W[j];
        ws[689] = acc;
    } else if (t == 546) {               // ce2
        float acc = 0.f;
        for (int j = 0; j < HID; ++j) acc += e2_b[j] * pol_W[j];
        s_ce2 = acc;
    } else if (t == 547) {
        ws[691] = pol_b[0];
    }
    __syncthreads();
    if (t < 272) {                       // w1 = e1_W @ qEE
        float acc = 0.f;
        for (int j = 0; j < HID; ++j) acc += e1_W[t * HID + j] * qEE[j];
        ws[416 + t] = acc;
    } else if (t == 272) {               // ce = e1_b.qEE + e2_b.p
        float acc = 0.f;
        for (int j = 0; j < HID; ++j) acc += e1_b[j] * qEE[j];
        ws[690] = acc + s_ce2;
    }
}

// One wave (64 lanes) per output action. Each action = sum of 4 consecutive
// action rows, all guaranteed in the same branch (branch size 100000 % 4 == 0).
// Lane l handles float2 slice [2l, 2l+1] of every 128-vector (one coalesced
// 512B load per vector per wave); feat-16 handled by lanes 0..7.
__global__ __launch_bounds__(256) void actions_kernel(
    const float* __restrict__ globs, const float* __restrict__ nodes,
    const float* __restrict__ edges,
    const float* __restrict__ ag, const float* __restrict__ an,
    const float* __restrict__ ae,
    const int* __restrict__ row, const int* __restrict__ col,
    const int* __restrict__ U, const int* __restrict__ V,
    const int* __restrict__ E,
    const float* __restrict__ ws, float* __restrict__ out)
{
    const int wave = threadIdx.x >> 6;
    const int lane = threadIdx.x & 63;
    const int a = blockIdx.x * 4 + wave;      // grid = NUM_ACTIONS/4 exactly
    const int r0 = a * 4;                     // first action row of this action

    float p = 0.f;
    float cpart;

    if (r0 < N_PER) {
        // ---- glob branch ----
        const float2 w  = *(const float2*)&ws[2 * lane];
        float2 wf = make_float2(0.f, 0.f);
        if (lane < 8) wf = *(const float2*)&ws[HID + 2 * lane];
        #pragma unroll
        for (int i = 0; i < 4; ++i) {
            const int g = r0 + i;
            const int u = U[g];
            const float2 x = *(const float2*)&globs[u * HID + 2 * lane];
            p += x.x * w.x + x.y * w.y;
            if (lane < 8) {
                const float2 f = *(const float2*)&ag[g * FEAT + 2 * lane];
                p += f.x * wf.x + f.y * wf.y;
            }
        }
        cpart = 4.f * ws[688];
    } else if (r0 < 2 * N_PER) {
        // ---- node branch ----
        const float2 w  = *(const float2*)&ws[144 + 2 * lane];
        float2 wf = make_float2(0.f, 0.f);
        if (lane < 8) wf = *(const float2*)&ws[144 + HID + 2 * lane];
        const int gb = r0 - N_PER;
        #pragma unroll
        for (int i = 0; i < 4; ++i) {
            const int g = gb + i;
            const int v = V[g];
            const float2 x = *(const float2*)&nodes[v * HID + 2 * lane];
            p += x.x * w.x + x.y * w.y;
            if (lane < 8) {
                const float2 f = *(const float2*)&an[g * FEAT + 2 * lane];
                p += f.x * wf.x + f.y * wf.y;
            }
        }
        cpart = 4.f * ws[689];
    } else {
        // ---- edge branch ----
        const float2 we = *(const float2*)&ws[288 + 2 * lane];        // qe
        const float2 wr = *(const float2*)&ws[416 + 2 * lane];        // w1[0:128]
        const float2 wc = *(const float2*)&ws[416 + 144 + 2 * lane];  // w1[144:272]
        float2 wf = make_float2(0.f, 0.f);
        if (lane < 8) wf = *(const float2*)&ws[416 + HID + 2 * lane]; // w1[128:144]
        const int gb = r0 - 2 * N_PER;
        #pragma unroll
        for (int i = 0; i < 4; ++i) {
            const int g = gb + i;
            const int e  = E[g];
            const int re = row[e];
            const int ce = col[e];
            const float2 xe = *(const float2*)&edges[e  * HID + 2 * lane];
            const float2 xr = *(const float2*)&nodes[re * HID + 2 * lane];
            const float2 xc = *(const float2*)&nodes[ce * HID + 2 * lane];
            p += xe.x * we.x + xe.y * we.y;
            p += xr.x * wr.x + xr.y * wr.y;
            p += xc.x * wc.x + xc.y * wc.y;
            if (lane < 8) {
                const float2 f = *(const float2*)&ae[g * FEAT + 2 * lane];
                p += f.x * wf.x + f.y * wf.y;
            }
        }
        cpart = 4.f * ws[690];
    }

    // wave reduction over 64 lanes
    #pragma unroll
    for (int m = 32; m; m >>= 1) p += __shfl_xor(p, m);

    if (lane == 0) out[a] = p + cpart + ws[691];
}

extern "C" void kernel_launch(void* const* d_in, const int* in_sizes, int n_in,
                              void* d_out, int out_size, void* d_ws, size_t ws_size,
                              hipStream_t stream)
{
    const float* globs  = (const float*)d_in[0];
    const float* nodes  = (const float*)d_in[1];
    const float* edges  = (const float*)d_in[2];
    const float* ag     = (const float*)d_in[3];
    const float* an     = (const float*)d_in[4];
    const float* ae     = (const float*)d_in[5];
    const float* glob_W = (const float*)d_in[6];
    const float* glob_b = (const float*)d_in[7];
    const float* node_W = (const float*)d_in[8];
    const float* node_b = (const float*)d_in[9];
    const float* e1_W   = (const float*)d_in[10];
    const float* e1_b   = (const float*)d_in[11];
    const float* e2_W   = (const float*)d_in[12];
    const float* e2_b   = (const float*)d_in[13];
    const float* pol_W  = (const float*)d_in[14];
    const float* pol_b  = (const float*)d_in[15];
    const int*   row    = (const int*)d_in[16];
    const int*   col    = (const int*)d_in[17];
    const int*   U      = (const int*)d_in[18];
    const int*   V      = (const int*)d_in[20];
    const int*   E      = (const int*)d_in[22];

    float* ws  = (float*)d_ws;
    float* out = (float*)d_out;

    hipLaunchKernelGGL(fold_weights_kernel, dim3(1), dim3(1024), 0, stream,
                       glob_W, glob_b, node_W, node_b, e1_W, e1_b, e2_W, e2_b,
                       pol_W, pol_b, ws);
    hipLaunchKernelGGL(actions_kernel, dim3(NUM_ACTIONS / 4), dim3(256), 0, stream,
                       globs, nodes, edges, ag, an, ae, row, col, U, V, E, ws, out);
}

// Round 2
// 74.147 us; speedup vs baseline: 1.0605x; 1.0605x over previous
//
#include <hip/hip_runtime.h>

#define HID 128
#define FEAT 16
#define N_PER 100000
#define NUM_ACTIONS 75000

// ws float layout:
// [0..143]   wg   = glob_W @ p            (144)
// [144..287] wn   = node_W @ p            (144)
// [288..415] qe   = (e2_W @ p)[0:128]     (128)
// [416..687] w1   = e1_W @ (e2_W@p)[128:] (272)  (row:416..543, feat:544..559, col:560..687)
// [688] cg = glob_b.p   [689] cn = node_b.p
// [690] ce = e1_b.qEE + e2_b.p            [691] pb = pol_b

// Wave-coalesced fold: each wave computes dot(W_row, vec) with float2/lane
// reads + 6-step shfl reduce. Phase A: 547 dots vs pol_W. Phase B (needs
// qEE from A): 273 dots vs qEE.
__global__ __launch_bounds__(1024) void fold_weights_kernel(
    const float* __restrict__ glob_W, const float* __restrict__ glob_b,
    const float* __restrict__ node_W, const float* __restrict__ node_b,
    const float* __restrict__ e1_W,  const float* __restrict__ e1_b,
    const float* __restrict__ e2_W,  const float* __restrict__ e2_b,
    const float* __restrict__ pol_W, const float* __restrict__ pol_b,
    float* __restrict__ ws)
{
    __shared__ float qEE[HID];
    __shared__ float s_ce2;
    const int t    = threadIdx.x;
    const int wave = t >> 6;          // 0..15
    const int lane = t & 63;

    const float2 p2 = *(const float2*)&pol_W[2 * lane];

    // ---- Phase A: dots against pol_W ----
    for (int d = wave; d < 547; d += 16) {
        const float* rowp;
        if      (d < 144) rowp = glob_W + d * HID;
        else if (d < 288) rowp = node_W + (d - 144) * HID;
        else if (d < 544) rowp = e2_W  + (d - 288) * HID;
        else if (d == 544) rowp = glob_b;
        else if (d == 545) rowp = node_b;
        else               rowp = e2_b;

        const float2 x = *(const float2*)&rowp[2 * lane];
        float acc = x.x * p2.x + x.y * p2.y;
        #pragma unroll
        for (int m = 32; m; m >>= 1) acc += __shfl_xor(acc, m);

        if (lane == 0) {
            if      (d < 288)  ws[d] = acc;
            else if (d < 544) {
                const int k = d - 288;
                if (k < HID) ws[288 + k] = acc;
                else         qEE[k - HID] = acc;
            }
            else if (d == 544) ws[688] = acc;
            else if (d == 545) ws[689] = acc;
            else               s_ce2 = acc;
        }
    }
    if (t == 0) ws[691] = pol_b[0];
    __syncthreads();

    // ---- Phase B: dots against qEE ----
    const float2 q2 = *(const float2*)&qEE[2 * lane];
    for (int d = wave; d < 273; d += 16) {
        const float* rowp = (d < 272) ? (e1_W + d * HID) : e1_b;
        const float2 x = *(const float2*)&rowp[2 * lane];
        float acc = x.x * q2.x + x.y * q2.y;
        #pragma unroll
        for (int m = 32; m; m >>= 1) acc += __shfl_xor(acc, m);
        if (lane == 0) {
            if (d < 272) ws[416 + d] = acc;
            else         ws[690] = acc + s_ce2;
        }
    }
}

__device__ __forceinline__ float dot4(float4 a, float4 b) {
    return a.x * b.x + a.y * b.y + a.z * b.z + a.w * b.w;
}

// Half-wave design: each 32-lane half owns one action (4 consecutive action
// rows, always same branch since branch size 100000 and pairs never straddle
// the even boundaries 25000/50000). Sublane s reads float4 at offset 4s:
// 32 x 16B = 512B coalesced row read. 2 actions per wave.
__global__ __launch_bounds__(256) void actions_kernel(
    const float* __restrict__ globs, const float* __restrict__ nodes,
    const float* __restrict__ edges,
    const float* __restrict__ ag, const float* __restrict__ an,
    const float* __restrict__ ae,
    const int* __restrict__ row, const int* __restrict__ col,
    const int* __restrict__ U, const int* __restrict__ V,
    const int* __restrict__ E,
    const float* __restrict__ ws, float* __restrict__ out)
{
    const int tid  = threadIdx.x;
    const int wave = tid >> 6;
    const int half = (tid >> 5) & 1;
    const int s    = tid & 31;
    const int a    = blockIdx.x * 8 + wave * 2 + half;   // action id
    const int r0   = a * 4;                              // first action row
    const int c4   = 4 * s;                              // float offset

    float p = 0.f;
    float cpart;

    if (r0 < N_PER) {
        // ---- glob branch ----
        const float4 w = *(const float4*)&ws[c4];
        float4 wf = make_float4(0.f, 0.f, 0.f, 0.f);
        if (s < 4) wf = *(const float4*)&ws[HID + c4];
        int u[4];
        #pragma unroll
        for (int i = 0; i < 4; ++i) u[i] = U[r0 + i];
        #pragma unroll
        for (int i = 0; i < 4; ++i) {
            const float4 x = *(const float4*)&globs[u[i] * HID + c4];
            p += dot4(x, w);
        }
        if (s < 4) {
            #pragma unroll
            for (int i = 0; i < 4; ++i) {
                const float4 f = *(const float4*)&ag[(r0 + i) * FEAT + c4];
                p += dot4(f, wf);
            }
        }
        cpart = 4.f * ws[688];
    } else if (r0 < 2 * N_PER) {
        // ---- node branch ----
        const float4 w = *(const float4*)&ws[144 + c4];
        float4 wf = make_float4(0.f, 0.f, 0.f, 0.f);
        if (s < 4) wf = *(const float4*)&ws[144 + HID + c4];
        const int gb = r0 - N_PER;
        int v[4];
        #pragma unroll
        for (int i = 0; i < 4; ++i) v[i] = V[gb + i];
        #pragma unroll
        for (int i = 0; i < 4; ++i) {
            const float4 x = *(const float4*)&nodes[v[i] * HID + c4];
            p += dot4(x, w);
        }
        if (s < 4) {
            #pragma unroll
            for (int i = 0; i < 4; ++i) {
                const float4 f = *(const float4*)&an[(gb + i) * FEAT + c4];
                p += dot4(f, wf);
            }
        }
        cpart = 4.f * ws[689];
    } else {
        // ---- edge branch ----
        const float4 we = *(const float4*)&ws[288 + c4];        // qe
        const float4 wr = *(const float4*)&ws[416 + c4];        // w1 row part
        const float4 wc = *(const float4*)&ws[560 + c4];        // w1 col part
        float4 wf = make_float4(0.f, 0.f, 0.f, 0.f);
        if (s < 4) wf = *(const float4*)&ws[544 + c4];          // w1 feat part
        const int gb = r0 - 2 * N_PER;
        int e[4];
        #pragma unroll
        for (int i = 0; i < 4; ++i) e[i] = E[gb + i];
        int re[4], ce[4];
        #pragma unroll
        for (int i = 0; i < 4; ++i) { re[i] = row[e[i]]; ce[i] = col[e[i]]; }
        #pragma unroll
        for (int i = 0; i < 4; ++i) {
            const float4 xe = *(const float4*)&edges[e[i]  * HID + c4];
            const float4 xr = *(const float4*)&nodes[re[i] * HID + c4];
            const float4 xc = *(const float4*)&nodes[ce[i] * HID + c4];
            p += dot4(xe, we) + dot4(xr, wr) + dot4(xc, wc);
        }
        if (s < 4) {
            #pragma unroll
            for (int i = 0; i < 4; ++i) {
                const float4 f = *(const float4*)&ae[(gb + i) * FEAT + c4];
                p += dot4(f, wf);
            }
        }
        cpart = 4.f * ws[690];
    }

    // reduce over the 32-lane half (xor masks <32 stay within the half)
    #pragma unroll
    for (int m = 16; m; m >>= 1) p += __shfl_xor(p, m);

    if (s == 0) out[a] = p + cpart + ws[691];
}

extern "C" void kernel_launch(void* const* d_in, const int* in_sizes, int n_in,
                              void* d_out, int out_size, void* d_ws, size_t ws_size,
                              hipStream_t stream)
{
    const float* globs  = (const float*)d_in[0];
    const float* nodes  = (const float*)d_in[1];
    const float* edges  = (const float*)d_in[2];
    const float* ag     = (const float*)d_in[3];
    const float* an     = (const float*)d_in[4];
    const float* ae     = (const float*)d_in[5];
    const float* glob_W = (const float*)d_in[6];
    const float* glob_b = (const float*)d_in[7];
    const float* node_W = (const float*)d_in[8];
    const float* node_b = (const float*)d_in[9];
    const float* e1_W   = (const float*)d_in[10];
    const float* e1_b   = (const float*)d_in[11];
    const float* e2_W   = (const float*)d_in[12];
    const float* e2_b   = (const float*)d_in[13];
    const float* pol_W  = (const float*)d_in[14];
    const float* pol_b  = (const float*)d_in[15];
    const int*   row    = (const int*)d_in[16];
    const int*   col    = (const int*)d_in[17];
    const int*   U      = (const int*)d_in[18];
    const int*   V      = (const int*)d_in[20];
    const int*   E      = (const int*)d_in[22];

    float* ws  = (float*)d_ws;
    float* out = (float*)d_out;

    hipLaunchKernelGGL(fold_weights_kernel, dim3(1), dim3(1024), 0, stream,
                       glob_W, glob_b, node_W, node_b, e1_W, e1_b, e2_W, e2_b,
                       pol_W, pol_b, ws);
    hipLaunchKernelGGL(actions_kernel, dim3(NUM_ACTIONS / 8), dim3(256), 0, stream,
                       globs, nodes, edges, ag, an, ae, row, col, U, V, E, ws, out);
}

// Round 3
// 40.215 us; speedup vs baseline: 1.9553x; 1.8438x over previous
//
#include <hip/hip_runtime.h>

#define HID 128
#define FEAT 16
#define N_PER 100000
#define NUM_ACTIONS 75000
#define N_NODES 100000
#define N_GRAPHS 512

// ws float layout:
// [0..143]   wg   = glob_W @ p   (globs part 0..127, feat part 128..143)
// [144..287] wn   = node_W @ p   (nodes part 144..271, feat part 272..287)
// [288..415] qe   = (e2_W @ p)[0:128]
// [416..687] w1   = e1_W @ qEE   (row 416..543, feat 544..559, col 560..687)
// [688] cg=glob_b.p  [689] cn=node_b.p  [690] ce=e1_b.qEE+e2_b.p  [691] pb
// [1024 ..]             nscal: float4 per node (x=.wr, y=.wc, z=.wn)
// [1024+4*N_NODES ..]   gscal: float per graph
#define NSCAL_OFF 1024
#define GSCAL_OFF (NSCAL_OFF + 4 * N_NODES)

__device__ __forceinline__ float dot4(float4 a, float4 b) {
    return a.x * b.x + a.y * b.y + a.z * b.z + a.w * b.w;
}

// 32 blocks x 16 waves. Phase 0: every block computes qEE[128] (redundant,
// 64KB L2 read). Phase 1: 512 waves grid-stride the 692 folded dots, each a
// wave-coalesced float2 row read + 6-step shfl reduce.
__global__ __launch_bounds__(1024) void fold_kernel(
    const float* __restrict__ glob_W, const float* __restrict__ glob_b,
    const float* __restrict__ node_W, const float* __restrict__ node_b,
    const float* __restrict__ e1_W,  const float* __restrict__ e1_b,
    const float* __restrict__ e2_W,  const float* __restrict__ e2_b,
    const float* __restrict__ pol_W, const float* __restrict__ pol_b,
    float* __restrict__ ws)
{
    __shared__ float qEE[HID];
    const int t = threadIdx.x, wave = t >> 6, lane = t & 63;
    const float2 p2 = *(const float2*)&pol_W[2 * lane];

    for (int k = wave; k < HID; k += 16) {
        const float2 x = *(const float2*)&e2_W[(HID + k) * HID + 2 * lane];
        float acc = x.x * p2.x + x.y * p2.y;
        #pragma unroll
        for (int m = 32; m; m >>= 1) acc += __shfl_xor(acc, m);
        if (lane == 0) qEE[k] = acc;
    }
    __syncthreads();
    const float2 q2 = *(const float2*)&qEE[2 * lane];

    const int gw = blockIdx.x * 16 + wave;
    for (int d = gw; d < 692; d += 512) {
        float acc;
        if (d < 144) {
            const float2 x = *(const float2*)&glob_W[d * HID + 2 * lane];
            acc = x.x * p2.x + x.y * p2.y;
        } else if (d < 288) {
            const float2 x = *(const float2*)&node_W[(d - 144) * HID + 2 * lane];
            acc = x.x * p2.x + x.y * p2.y;
        } else if (d < 416) {
            const float2 x = *(const float2*)&e2_W[(d - 288) * HID + 2 * lane];
            acc = x.x * p2.x + x.y * p2.y;
        } else if (d < 688) {
            const float2 x = *(const float2*)&e1_W[(d - 416) * HID + 2 * lane];
            acc = x.x * q2.x + x.y * q2.y;
        } else if (d == 688) {
            const float2 x = *(const float2*)&glob_b[2 * lane];
            acc = x.x * p2.x + x.y * p2.y;
        } else if (d == 689) {
            const float2 x = *(const float2*)&node_b[2 * lane];
            acc = x.x * p2.x + x.y * p2.y;
        } else if (d == 690) {
            const float2 x1 = *(const float2*)&e1_b[2 * lane];
            const float2 x2 = *(const float2*)&e2_b[2 * lane];
            acc = x1.x * q2.x + x1.y * q2.y + x2.x * p2.x + x2.y * p2.y;
        } else {
            if (lane == 0) ws[691] = pol_b[0];
            continue;
        }
        #pragma unroll
        for (int m = 32; m; m >>= 1) acc += __shfl_xor(acc, m);
        if (lane == 0) ws[d] = acc;
    }
}

// Streaming precompute: half-wave per node row (fully coalesced sequential
// 512B reads), 3 dots (wr, wc, wn) -> nscal float4. Tail halves do gscal.
__global__ __launch_bounds__(256) void precompute_kernel(
    const float* __restrict__ nodes, const float* __restrict__ globs,
    float* __restrict__ ws)
{
    const int t = threadIdx.x, s = t & 31;
    const int h = blockIdx.x * 8 + (t >> 5);
    if (h < N_NODES) {
        const float4 fr = *(const float4*)&ws[416 + 4 * s];
        const float4 fc = *(const float4*)&ws[560 + 4 * s];
        const float4 fn = *(const float4*)&ws[144 + 4 * s];
        const float4 x  = *(const float4*)&nodes[h * HID + 4 * s];
        float ar = dot4(x, fr), ac = dot4(x, fc), an_ = dot4(x, fn);
        #pragma unroll
        for (int m = 16; m; m >>= 1) {
            ar  += __shfl_xor(ar, m);
            ac  += __shfl_xor(ac, m);
            an_ += __shfl_xor(an_, m);
        }
        if (s == 0) *(float4*)&ws[NSCAL_OFF + 4 * h] = make_float4(ar, ac, an_, 0.f);
    } else if (h < N_NODES + N_GRAPHS) {
        const int u = h - N_NODES;
        const float4 fg = *(const float4*)&ws[4 * s];
        const float4 x  = *(const float4*)&globs[u * HID + 4 * s];
        float a = dot4(x, fg);
        #pragma unroll
        for (int m = 16; m; m >>= 1) a += __shfl_xor(a, m);
        if (s == 0) ws[GSCAL_OFF + u] = a;
    }
}

// Each block: wave0 = 1 glob-wave (4 actions, 16 lanes each),
// wave1 = 1 node-wave (4 actions), wave2+3 = 2 edge-waves (2 actions each,
// 32 lanes per action). Uniform work per block.
__global__ __launch_bounds__(256) void actions_kernel(
    const float* __restrict__ edges,
    const float* __restrict__ ag, const float* __restrict__ an,
    const float* __restrict__ ae,
    const int* __restrict__ row, const int* __restrict__ col,
    const int* __restrict__ U, const int* __restrict__ V,
    const int* __restrict__ E,
    const float* __restrict__ ws, float* __restrict__ out)
{
    const int b    = blockIdx.x;            // 0..6249
    const int wave = threadIdx.x >> 6;
    const int lane = threadIdx.x & 63;

    if (wave < 2) {
        const bool isg = (wave == 0);
        const int qtr = lane >> 4, ql = lane & 15;
        const int al  = 4 * b + qtr;          // branch-local action
        const int gl  = 4 * al;               // branch-local row base
        const float* feats = isg ? ag : an;
        const int* idx     = isg ? U : V;
        const int wbase    = isg ? 0 : 144;

        const float4 f  = *(const float4*)&feats[gl * FEAT + 4 * ql];
        const float4 wf = *(const float4*)&ws[wbase + HID + 4 * (ql & 3)];
        float p = dot4(f, wf);
        if ((ql & 3) == 0) {
            const int id = idx[gl + (ql >> 2)];
            p += isg ? ws[GSCAL_OFF + id] : ws[NSCAL_OFF + 4 * id + 2];
        }
        #pragma unroll
        for (int m = 8; m; m >>= 1) p += __shfl_xor(p, m);
        if (ql == 0)
            out[(isg ? 0 : 25000) + al] = p + 4.f * ws[isg ? 688 : 689] + ws[691];
    } else {
        const int j = b + 6250 * (wave - 2);  // 0..12499
        const int s = lane & 31;
        const int al = 2 * j + (lane >> 5);   // branch-local action 0..24999
        const int gl = 4 * al;                // branch-local row base
        const float4 we = *(const float4*)&ws[288 + 4 * s];
        int e[4];
        #pragma unroll
        for (int i = 0; i < 4; ++i) e[i] = E[gl + i];
        float p = 0.f;
        #pragma unroll
        for (int i = 0; i < 4; ++i) {
            const float4 x = *(const float4*)&edges[e[i] * HID + 4 * s];
            p += dot4(x, we);
        }
        if (s < 16) {
            const float4 f  = *(const float4*)&ae[gl * FEAT + 4 * s];
            const float4 wf = *(const float4*)&ws[544 + 4 * (s & 3)];
            p += dot4(f, wf);
        }
        if ((s & 3) == 0) {
            const int i = (s >> 2) & 3;
            if (s < 16) p += ws[NSCAL_OFF + 4 * row[e[i]] + 0];
            else        p += ws[NSCAL_OFF + 4 * col[e[i]] + 1];
        }
        #pragma unroll
        for (int m = 16; m; m >>= 1) p += __shfl_xor(p, m);
        if (s == 0) out[50000 + al] = p + 4.f * ws[690] + ws[691];
    }
}

extern "C" void kernel_launch(void* const* d_in, const int* in_sizes, int n_in,
                              void* d_out, int out_size, void* d_ws, size_t ws_size,
                              hipStream_t stream)
{
    const float* globs  = (const float*)d_in[0];
    const float* nodes  = (const float*)d_in[1];
    const float* edges  = (const float*)d_in[2];
    const float* ag     = (const float*)d_in[3];
    const float* an     = (const float*)d_in[4];
    const float* ae     = (const float*)d_in[5];
    const float* glob_W = (const float*)d_in[6];
    const float* glob_b = (const float*)d_in[7];
    const float* node_W = (const float*)d_in[8];
    const float* node_b = (const float*)d_in[9];
    const float* e1_W   = (const float*)d_in[10];
    const float* e1_b   = (const float*)d_in[11];
    const float* e2_W   = (const float*)d_in[12];
    const float* e2_b   = (const float*)d_in[13];
    const float* pol_W  = (const float*)d_in[14];
    const float* pol_b  = (const float*)d_in[15];
    const int*   row    = (const int*)d_in[16];
    const int*   col    = (const int*)d_in[17];
    const int*   U      = (const int*)d_in[18];
    const int*   V      = (const int*)d_in[20];
    const int*   E      = (const int*)d_in[22];

    float* ws  = (float*)d_ws;
    float* out = (float*)d_out;

    hipLaunchKernelGGL(fold_kernel, dim3(32), dim3(1024), 0, stream,
                       glob_W, glob_b, node_W, node_b, e1_W, e1_b, e2_W, e2_b,
                       pol_W, pol_b, ws);
    hipLaunchKernelGGL(precompute_kernel, dim3((N_NODES + N_GRAPHS + 7) / 8), dim3(256),
                       0, stream, nodes, globs, ws);
    hipLaunchKernelGGL(actions_kernel, dim3(6250), dim3(256), 0, stream,
                       edges, ag, an, ae, row, col, U, V, E, ws, out);
}